// Round 1
// baseline (641.535 us; speedup 1.0000x reference)
//
#include <hip/hip_runtime.h>
#include <cstdint>
#include <cstddef>

#define SEQ    2048
#define BATCH  2
#define HID    768
#define NH     12
#define HD     64
#define QKV_N  2304

static constexpr float ATT_SCALE = 0.125f;  // 64^-0.5

// ---------------------------------------------------------------------------
// GEMM NT: C[M,N] = A[M,K] * B[N,K]^T (+ optional bias[N])
// Both A and B are row-major with contiguous K (dot products of rows).
// 64x64 block tile, 256 threads (16x16), 4x4 outputs per thread, K-chunk 16.
// LDS tiles stored transposed [k][m] with stride 68 so inner-loop reads are
// float4, 16B-aligned, and bank-conflict-free (A side) / 2-way free (B side).
// ---------------------------------------------------------------------------
__global__ __launch_bounds__(256)
void gemm_nt(const float* __restrict__ A, const float* __restrict__ B,
             const float* __restrict__ bias, float* __restrict__ C,
             int M, int N, int K) {
  __shared__ float As[16][68];
  __shared__ float Bs[16][68];

  const int t  = threadIdx.x;
  const int tx = t & 15;        // output col group
  const int ty = t >> 4;        // output row group
  const int m0 = blockIdx.y * 64;
  const int n0 = blockIdx.x * 64;

  const int lr = t >> 2;        // 0..63 : tile row this thread loads
  const int lk = (t & 3) * 4;   // 0,4,8,12 : k-offset this thread loads

  const float* Ap = A + (size_t)(m0 + lr) * K + lk;
  const float* Bp = B + (size_t)(n0 + lr) * K + lk;

  float acc[4][4] = {};

  for (int k0 = 0; k0 < K; k0 += 16) {
    const float4 av = *reinterpret_cast<const float4*>(Ap + k0);
    const float4 bv = *reinterpret_cast<const float4*>(Bp + k0);
    __syncthreads();   // prior iteration's LDS reads complete
    As[lk + 0][lr] = av.x; As[lk + 1][lr] = av.y;
    As[lk + 2][lr] = av.z; As[lk + 3][lr] = av.w;
    Bs[lk + 0][lr] = bv.x; Bs[lk + 1][lr] = bv.y;
    Bs[lk + 2][lr] = bv.z; Bs[lk + 3][lr] = bv.w;
    __syncthreads();
#pragma unroll
    for (int kk = 0; kk < 16; ++kk) {
      const float4 a4 = *reinterpret_cast<const float4*>(&As[kk][ty * 4]);
      const float4 b4 = *reinterpret_cast<const float4*>(&Bs[kk][tx * 4]);
      const float ar[4] = {a4.x, a4.y, a4.z, a4.w};
      const float br[4] = {b4.x, b4.y, b4.z, b4.w};
#pragma unroll
      for (int i = 0; i < 4; ++i)
#pragma unroll
        for (int j = 0; j < 4; ++j)
          acc[i][j] = fmaf(ar[i], br[j], acc[i][j]);
    }
  }

  float4 bv4 = make_float4(0.f, 0.f, 0.f, 0.f);
  if (bias) bv4 = *reinterpret_cast<const float4*>(&bias[n0 + tx * 4]);
#pragma unroll
  for (int i = 0; i < 4; ++i) {
    float4 ov;
    ov.x = acc[i][0] + bv4.x;
    ov.y = acc[i][1] + bv4.y;
    ov.z = acc[i][2] + bv4.z;
    ov.w = acc[i][3] + bv4.w;
    *reinterpret_cast<float4*>(&C[(size_t)(m0 + ty * 4 + i) * N + n0 + tx * 4]) = ov;
  }
}

// ---------------------------------------------------------------------------
// Flash-style attention, fp32.
// Grid: (BATCH*NH, SEQ/64). Block: 256 threads.
// qkv layout: [B*SEQ, 2304] where col = qkv_idx*768 + h*64 + d.
// att layout: [B*SEQ, 768]  (col = h*64 + d) -> feeds out-proj directly.
// Q, K stored in LDS transposed [d][row] (stride 68); V row-major [y][d].
// Per kv-tile: scores (64 steps x 16 FMA), online softmax (shfl over 16
// lanes), P written transposed [y][r], then PV (64 steps x 16 FMA).
// ---------------------------------------------------------------------------
__global__ __launch_bounds__(256)
void attn_fp32(const float* __restrict__ qkv, float* __restrict__ att) {
  const int bh = blockIdx.x;           // 0..23
  const int qt = blockIdx.y;           // 0..31
  const int b  = bh / NH;
  const int h  = bh % NH;

  const float* baseq = qkv + (size_t)b * SEQ * QKV_N + h * HD;
  const float* Kg    = baseq + HID;
  const float* Vg    = baseq + 2 * HID;

  __shared__ float Qts[64][68];  // [d][r], pre-scaled by ATT_SCALE
  __shared__ float Kts[64][68];  // [d][c]
  __shared__ float Vs [64][68];  // [y][d]
  __shared__ float Pst[64][68];  // [y][r]

  const int t   = threadIdx.x;
  const int tx  = t & 15;        // col group (head-dim / kv idx)
  const int tyg = t >> 4;        // row group (q rows)
  const int q0  = qt * 64;

  // ---- load Q tile transposed, pre-scaled ----
  {
    const int r  = t >> 2;
    const int c0 = (t & 3) * 4;
#pragma unroll
    for (int it = 0; it < 4; ++it) {
      const int c4 = c0 + it * 16;
      const float4 v = *reinterpret_cast<const float4*>(
          &baseq[(size_t)(q0 + r) * QKV_N + c4]);
      Qts[c4 + 0][r] = v.x * ATT_SCALE;
      Qts[c4 + 1][r] = v.y * ATT_SCALE;
      Qts[c4 + 2][r] = v.z * ATT_SCALE;
      Qts[c4 + 3][r] = v.w * ATT_SCALE;
    }
  }

  float o[4][4] = {};
  float mrow[4], lrow[4];
#pragma unroll
  for (int i = 0; i < 4; ++i) { mrow[i] = -1e30f; lrow[i] = 0.f; }

  for (int y0 = 0; y0 < SEQ; y0 += 64) {
    __syncthreads();  // Q visible (first iter) / prior PV reads done (later)

    // ---- stage K (transposed) and V (row-major) ----
    {
      const int r  = t >> 2;
      const int c0 = (t & 3) * 4;
#pragma unroll
      for (int it = 0; it < 4; ++it) {
        const int c4 = c0 + it * 16;
        const float4 kv = *reinterpret_cast<const float4*>(
            &Kg[(size_t)(y0 + r) * QKV_N + c4]);
        Kts[c4 + 0][r] = kv.x; Kts[c4 + 1][r] = kv.y;
        Kts[c4 + 2][r] = kv.z; Kts[c4 + 3][r] = kv.w;
      }
      const int vr = t >> 4;          // 0..15
      const int vc = (t & 15) * 4;    // 0..60
#pragma unroll
      for (int it = 0; it < 4; ++it) {
        const int y = vr + it * 16;
        const float4 vv = *reinterpret_cast<const float4*>(
            &Vg[(size_t)(y0 + y) * QKV_N + vc]);
        *reinterpret_cast<float4*>(&Vs[y][vc]) = vv;
      }
    }
    __syncthreads();

    // ---- scores: s[i][j] = sum_d Q[r_i][d] * K[c_j][d] (Q pre-scaled) ----
    float s[4][4] = {};
#pragma unroll 8
    for (int d = 0; d < 64; ++d) {
      const float4 q4 = *reinterpret_cast<const float4*>(&Qts[d][tyg * 4]);
      const float4 k4 = *reinterpret_cast<const float4*>(&Kts[d][tx * 4]);
      const float qr[4] = {q4.x, q4.y, q4.z, q4.w};
      const float kr[4] = {k4.x, k4.y, k4.z, k4.w};
#pragma unroll
      for (int i = 0; i < 4; ++i)
#pragma unroll
        for (int j = 0; j < 4; ++j)
          s[i][j] = fmaf(qr[i], kr[j], s[i][j]);
    }

    // ---- online softmax update ----
    float p[4][4];
#pragma unroll
    for (int i = 0; i < 4; ++i) {
      float pm = fmaxf(fmaxf(s[i][0], s[i][1]), fmaxf(s[i][2], s[i][3]));
      pm = fmaxf(pm, __shfl_xor(pm, 1, 16));
      pm = fmaxf(pm, __shfl_xor(pm, 2, 16));
      pm = fmaxf(pm, __shfl_xor(pm, 4, 16));
      pm = fmaxf(pm, __shfl_xor(pm, 8, 16));
      const float mnew = fmaxf(mrow[i], pm);
      const float corr = __expf(mrow[i] - mnew);
      mrow[i] = mnew;
      float psum = 0.f;
#pragma unroll
      for (int j = 0; j < 4; ++j) {
        p[i][j] = __expf(s[i][j] - mnew);
        psum += p[i][j];
      }
      lrow[i] = lrow[i] * corr + psum;
#pragma unroll
      for (int j = 0; j < 4; ++j) o[i][j] *= corr;
    }

    // ---- write P transposed [y][r] ----
#pragma unroll
    for (int i = 0; i < 4; ++i)
#pragma unroll
      for (int j = 0; j < 4; ++j)
        Pst[tx * 4 + j][tyg * 4 + i] = p[i][j];
    __syncthreads();

    // ---- PV: o[i][j] += sum_y P[r_i][y] * V[y][c_j] ----
#pragma unroll 8
    for (int y = 0; y < 64; ++y) {
      const float4 p4 = *reinterpret_cast<const float4*>(&Pst[y][tyg * 4]);
      const float4 v4 = *reinterpret_cast<const float4*>(&Vs[y][tx * 4]);
      const float pr[4] = {p4.x, p4.y, p4.z, p4.w};
      const float vr4[4] = {v4.x, v4.y, v4.z, v4.w};
#pragma unroll
      for (int i = 0; i < 4; ++i)
#pragma unroll
        for (int j = 0; j < 4; ++j)
          o[i][j] = fmaf(pr[i], vr4[j], o[i][j]);
    }
  }

  // ---- epilogue: reduce l across the 16 col-lanes, normalize, store ----
#pragma unroll
  for (int i = 0; i < 4; ++i) {
    float lt = lrow[i];
    lt += __shfl_xor(lt, 1, 16);
    lt += __shfl_xor(lt, 2, 16);
    lt += __shfl_xor(lt, 4, 16);
    lt += __shfl_xor(lt, 8, 16);
    const float linv = 1.f / lt;
    float4 ov;
    ov.x = o[i][0] * linv;
    ov.y = o[i][1] * linv;
    ov.z = o[i][2] * linv;
    ov.w = o[i][3] * linv;
    *reinterpret_cast<float4*>(
        &att[(size_t)(b * SEQ + q0 + tyg * 4 + i) * HID + h * HD + tx * 4]) = ov;
  }
}

// ---------------------------------------------------------------------------
extern "C" void kernel_launch(void* const* d_in, const int* in_sizes, int n_in,
                              void* d_out, int out_size, void* d_ws, size_t ws_size,
                              hipStream_t stream) {
  const float* x     = (const float*)d_in[0];  // [2,2048,768]
  const float* w_qkv = (const float*)d_in[1];  // [2304,768]
  const float* w_out = (const float*)d_in[2];  // [768,768]
  const float* b_out = (const float*)d_in[3];  // [768]
  float* out = (float*)d_out;                  // [2,2048,768]

  float* qkv = (float*)d_ws;                         // [4096, 2304] = 37.7 MB
  float* att = qkv + (size_t)BATCH * SEQ * QKV_N;    // [4096, 768]  = 12.6 MB
  // total workspace use: 50,331,648 bytes

  const dim3 blk(256);

  // QKV projection: [4096,2304] = x[4096,768] @ w_qkv[2304,768]^T
  gemm_nt<<<dim3(QKV_N / 64, (BATCH * SEQ) / 64), blk, 0, stream>>>(
      x, w_qkv, nullptr, qkv, BATCH * SEQ, QKV_N, HID);

  // attention -> att [4096, 768]
  attn_fp32<<<dim3(BATCH * NH, SEQ / 64), blk, 0, stream>>>(qkv, att);

  // out projection: out = att @ w_out^T + b_out
  gemm_nt<<<dim3(HID / 64, (BATCH * SEQ) / 64), blk, 0, stream>>>(
      att, w_out, b_out, out, BATCH * SEQ, HID, HID);
}

// Round 2
// 358.173 us; speedup vs baseline: 1.7911x; 1.7911x over previous
//
#include <hip/hip_runtime.h>
#include <hip/hip_bf16.h>
#include <cstdint>
#include <cstddef>

#define SEQ    2048
#define BATCH  2
#define HID    768
#define NH     12
#define HD     64
#define QKV_N  2304

typedef __attribute__((ext_vector_type(8))) short bf16x8;
typedef __attribute__((ext_vector_type(4))) float f32x4;

static __device__ __forceinline__ short f2bf(float x) {
  __hip_bfloat16 h = __float2bfloat16(x);  // RNE
  short s;
  __builtin_memcpy(&s, &h, 2);
  return s;
}

// ---------------------------------------------------------------------------
// fp32 GEMM NT (known-good from round 1): C[M,N] = A[M,K] * B[N,K]^T + bias
// ---------------------------------------------------------------------------
__global__ __launch_bounds__(256)
void gemm_nt(const float* __restrict__ A, const float* __restrict__ B,
             const float* __restrict__ bias, float* __restrict__ C,
             int M, int N, int K) {
  __shared__ float As[16][68];
  __shared__ float Bs[16][68];

  const int t  = threadIdx.x;
  const int tx = t & 15;
  const int ty = t >> 4;
  const int m0 = blockIdx.y * 64;
  const int n0 = blockIdx.x * 64;

  const int lr = t >> 2;
  const int lk = (t & 3) * 4;

  const float* Ap = A + (size_t)(m0 + lr) * K + lk;
  const float* Bp = B + (size_t)(n0 + lr) * K + lk;

  float acc[4][4] = {};

  for (int k0 = 0; k0 < K; k0 += 16) {
    const float4 av = *reinterpret_cast<const float4*>(Ap + k0);
    const float4 bv = *reinterpret_cast<const float4*>(Bp + k0);
    __syncthreads();
    As[lk + 0][lr] = av.x; As[lk + 1][lr] = av.y;
    As[lk + 2][lr] = av.z; As[lk + 3][lr] = av.w;
    Bs[lk + 0][lr] = bv.x; Bs[lk + 1][lr] = bv.y;
    Bs[lk + 2][lr] = bv.z; Bs[lk + 3][lr] = bv.w;
    __syncthreads();
#pragma unroll
    for (int kk = 0; kk < 16; ++kk) {
      const float4 a4 = *reinterpret_cast<const float4*>(&As[kk][ty * 4]);
      const float4 b4 = *reinterpret_cast<const float4*>(&Bs[kk][tx * 4]);
      const float ar[4] = {a4.x, a4.y, a4.z, a4.w};
      const float br[4] = {b4.x, b4.y, b4.z, b4.w};
#pragma unroll
      for (int i = 0; i < 4; ++i)
#pragma unroll
        for (int j = 0; j < 4; ++j)
          acc[i][j] = fmaf(ar[i], br[j], acc[i][j]);
    }
  }

  float4 bv4 = make_float4(0.f, 0.f, 0.f, 0.f);
  if (bias) bv4 = *reinterpret_cast<const float4*>(&bias[n0 + tx * 4]);
#pragma unroll
  for (int i = 0; i < 4; ++i) {
    float4 ov;
    ov.x = acc[i][0] + bv4.x;
    ov.y = acc[i][1] + bv4.y;
    ov.z = acc[i][2] + bv4.z;
    ov.w = acc[i][3] + bv4.w;
    *reinterpret_cast<float4*>(&C[(size_t)(m0 + ty * 4 + i) * N + n0 + tx * 4]) = ov;
  }
}

// ---------------------------------------------------------------------------
// Same fp32 GEMM but writes bf16 output (for qkv -> attention).
// ---------------------------------------------------------------------------
__global__ __launch_bounds__(256)
void gemm_nt_bf16(const float* __restrict__ A, const float* __restrict__ B,
                  short* __restrict__ C, int M, int N, int K) {
  __shared__ float As[16][68];
  __shared__ float Bs[16][68];

  const int t  = threadIdx.x;
  const int tx = t & 15;
  const int ty = t >> 4;
  const int m0 = blockIdx.y * 64;
  const int n0 = blockIdx.x * 64;

  const int lr = t >> 2;
  const int lk = (t & 3) * 4;

  const float* Ap = A + (size_t)(m0 + lr) * K + lk;
  const float* Bp = B + (size_t)(n0 + lr) * K + lk;

  float acc[4][4] = {};

  for (int k0 = 0; k0 < K; k0 += 16) {
    const float4 av = *reinterpret_cast<const float4*>(Ap + k0);
    const float4 bv = *reinterpret_cast<const float4*>(Bp + k0);
    __syncthreads();
    As[lk + 0][lr] = av.x; As[lk + 1][lr] = av.y;
    As[lk + 2][lr] = av.z; As[lk + 3][lr] = av.w;
    Bs[lk + 0][lr] = bv.x; Bs[lk + 1][lr] = bv.y;
    Bs[lk + 2][lr] = bv.z; Bs[lk + 3][lr] = bv.w;
    __syncthreads();
#pragma unroll
    for (int kk = 0; kk < 16; ++kk) {
      const float4 a4 = *reinterpret_cast<const float4*>(&As[kk][ty * 4]);
      const float4 b4 = *reinterpret_cast<const float4*>(&Bs[kk][tx * 4]);
      const float ar[4] = {a4.x, a4.y, a4.z, a4.w};
      const float br[4] = {b4.x, b4.y, b4.z, b4.w};
#pragma unroll
      for (int i = 0; i < 4; ++i)
#pragma unroll
        for (int j = 0; j < 4; ++j)
          acc[i][j] = fmaf(ar[i], br[j], acc[i][j]);
    }
  }

#pragma unroll
  for (int i = 0; i < 4; ++i) {
    short4 ov = make_short4(f2bf(acc[i][0]), f2bf(acc[i][1]),
                            f2bf(acc[i][2]), f2bf(acc[i][3]));
    *reinterpret_cast<short4*>(&C[(size_t)(m0 + ty * 4 + i) * N + n0 + tx * 4]) = ov;
  }
}

// ---------------------------------------------------------------------------
// Flash attention, bf16 MFMA (mfma_f32_16x16x32_bf16).
// Grid (BATCH*NH, SEQ/64), block 256 (4 waves). Wave w owns q-rows
// [q0+16w, q0+16w+16). qkv is bf16 [B*SEQ][2304], col = qkv*768 + h*64 + d.
//
// Fragment layouts (guide §3, m89-verified):
//   A: lane holds row = l&15,           k = (l>>4)*8 + j (+32 per chunk)
//   B: lane holds col = l&15,           k = (l>>4)*8 + j
//   D: lane holds row = (l>>4)*4 + reg, col = l&15
//
// K in LDS row-major [64][72] (pad 8 -> 2-way-free b128 reads).
// V in LDS transposed Vt[d][y ^ ((d>>4)<<4)]: XOR-y swizzle makes the
// scalar transpose writes bank-spread while 8-long y-runs stay contiguous
// (XOR only touches bits >=4) for aligned b128 B-fragment reads.
// P per-wave in LDS [16][72] (no cross-wave traffic -> no extra barrier).
// ---------------------------------------------------------------------------
__global__ __launch_bounds__(256)
void attn_mfma(const short* __restrict__ qkv, float* __restrict__ att) {
  const int bh = blockIdx.x;           // 0..23
  const int qt = blockIdx.y;           // 0..31
  const int b  = bh / NH;
  const int h  = bh % NH;
  const int q0 = qt * 64;

  const int t = threadIdx.x;
  const int w = t >> 6;                // wave 0..3
  const int l = t & 63;
  const int g = l >> 4;                // k-group 0..3
  const int n = l & 15;                // frag row/col index

  __shared__ short Kx[64][72];
  __shared__ short Vt[64][72];
  __shared__ short Ps[4][16][72];

  const short* baseq = qkv + (size_t)b * SEQ * QKV_N + h * HD;
  const short* Kg    = baseq + HID;
  const short* Vg    = baseq + 2 * HID;

  // ---- Q A-fragments: loaded once, kept in registers ----
  bf16x8 qf[2];
  {
    const short* qrow = baseq + (size_t)(q0 + w * 16 + n) * QKV_N;
#pragma unroll
    for (int c = 0; c < 2; ++c)
      qf[c] = *reinterpret_cast<const bf16x8*>(qrow + c * 32 + g * 8);
  }

  f32x4 o[4] = {{0.f,0.f,0.f,0.f},{0.f,0.f,0.f,0.f},
                {0.f,0.f,0.f,0.f},{0.f,0.f,0.f,0.f}};
  float mrow[4] = {-3e38f, -3e38f, -3e38f, -3e38f};
  float lrow[4] = {0.f, 0.f, 0.f, 0.f};

  const int sr  = t >> 2;              // staging row 0..63
  const int sdb = t & 3;               // staging 16-wide d block
  const int vys = sr ^ (sdb << 4);     // swizzled y for Vt writes

  for (int y0 = 0; y0 < SEQ; y0 += 64) {
    __syncthreads();   // previous tile's LDS reads complete

    // ---- stage K (row-major) ----
    {
      const short* kr = Kg + (size_t)(y0 + sr) * QKV_N + sdb * 16;
      bf16x8 k0 = *reinterpret_cast<const bf16x8*>(kr);
      bf16x8 k1 = *reinterpret_cast<const bf16x8*>(kr + 8);
      *reinterpret_cast<bf16x8*>(&Kx[sr][sdb * 16])     = k0;
      *reinterpret_cast<bf16x8*>(&Kx[sr][sdb * 16 + 8]) = k1;

      // ---- stage V (transposed, swizzled) ----
      const short* vr = Vg + (size_t)(y0 + sr) * QKV_N + sdb * 16;
      bf16x8 v0 = *reinterpret_cast<const bf16x8*>(vr);
      bf16x8 v1 = *reinterpret_cast<const bf16x8*>(vr + 8);
#pragma unroll
      for (int j = 0; j < 8; ++j) Vt[sdb * 16 + j][vys] = v0[j];
#pragma unroll
      for (int j = 0; j < 8; ++j) Vt[sdb * 16 + 8 + j][vys] = v1[j];
    }
    __syncthreads();

    // ---- QK^T: sc[kt][reg] = S[q = g*4+reg][y = kt*16 + n] ----
    f32x4 sc[4] = {{0.f,0.f,0.f,0.f},{0.f,0.f,0.f,0.f},
                   {0.f,0.f,0.f,0.f},{0.f,0.f,0.f,0.f}};
#pragma unroll
    for (int c = 0; c < 2; ++c) {
#pragma unroll
      for (int kt = 0; kt < 4; ++kt) {
        bf16x8 kb = *reinterpret_cast<const bf16x8*>(&Kx[kt * 16 + n][c * 32 + g * 8]);
        sc[kt] = __builtin_amdgcn_mfma_f32_16x16x32_bf16(qf[c], kb, sc[kt], 0, 0, 0);
      }
    }
#pragma unroll
    for (int kt = 0; kt < 4; ++kt)
#pragma unroll
      for (int r = 0; r < 4; ++r)
        sc[kt][r] *= 0.125f;   // exact pow2, matches ref's (q.k)*scale

    // ---- online softmax (per output row g*4 + r) ----
#pragma unroll
    for (int r = 0; r < 4; ++r) {
      float pm = fmaxf(fmaxf(sc[0][r], sc[1][r]), fmaxf(sc[2][r], sc[3][r]));
      pm = fmaxf(pm, __shfl_xor(pm, 1, 16));
      pm = fmaxf(pm, __shfl_xor(pm, 2, 16));
      pm = fmaxf(pm, __shfl_xor(pm, 4, 16));
      pm = fmaxf(pm, __shfl_xor(pm, 8, 16));
      const float mnew = fmaxf(mrow[r], pm);
      const float corr = __expf(mrow[r] - mnew);
      mrow[r] = mnew;
      float psum = 0.f;
#pragma unroll
      for (int kt = 0; kt < 4; ++kt) {
        const float p = __expf(sc[kt][r] - mnew);
        psum += p;
        Ps[w][g * 4 + r][kt * 16 + n] = f2bf(p);
      }
      lrow[r] = lrow[r] * corr + psum;
      o[0][r] *= corr; o[1][r] *= corr; o[2][r] *= corr; o[3][r] *= corr;
    }
    // Ps is wave-local: ds_write -> ds_read ordering handled by lgkmcnt.

    // ---- PV: o[dt][reg] += P[q][y] * V[y][d] ----
#pragma unroll
    for (int c = 0; c < 2; ++c) {
      bf16x8 pa = *reinterpret_cast<const bf16x8*>(&Ps[w][n][c * 32 + g * 8]);
#pragma unroll
      for (int dt = 0; dt < 4; ++dt) {
        bf16x8 vb = *reinterpret_cast<const bf16x8*>(
            &Vt[dt * 16 + n][(c * 32 + g * 8) ^ (dt << 4)]);
        o[dt] = __builtin_amdgcn_mfma_f32_16x16x32_bf16(pa, vb, o[dt], 0, 0, 0);
      }
    }
  }

  // ---- epilogue: reduce l over the 16 col lanes, normalize, store f32 ----
#pragma unroll
  for (int r = 0; r < 4; ++r) {
    float lt = lrow[r];
    lt += __shfl_xor(lt, 1, 16);
    lt += __shfl_xor(lt, 2, 16);
    lt += __shfl_xor(lt, 4, 16);
    lt += __shfl_xor(lt, 8, 16);
    const float linv = 1.f / lt;
    float* orow = att + (size_t)(b * SEQ + q0 + w * 16 + g * 4 + r) * HID
                      + h * HD + n;
    orow[0]  = o[0][r] * linv;
    orow[16] = o[1][r] * linv;
    orow[32] = o[2][r] * linv;
    orow[48] = o[3][r] * linv;
  }
}

// ---------------------------------------------------------------------------
extern "C" void kernel_launch(void* const* d_in, const int* in_sizes, int n_in,
                              void* d_out, int out_size, void* d_ws, size_t ws_size,
                              hipStream_t stream) {
  const float* x     = (const float*)d_in[0];  // [2,2048,768]
  const float* w_qkv = (const float*)d_in[1];  // [2304,768]
  const float* w_out = (const float*)d_in[2];  // [768,768]
  const float* b_out = (const float*)d_in[3];  // [768]
  float* out = (float*)d_out;                  // [2,2048,768]

  short* qkvb = (short*)d_ws;                              // bf16 [4096,2304] = 18.9 MB
  float* att  = (float*)((char*)d_ws + (size_t)BATCH * SEQ * QKV_N * 2);  // f32 [4096,768]

  const dim3 blk(256);

  // QKV projection (fp32 compute, bf16 output)
  gemm_nt_bf16<<<dim3(QKV_N / 64, (BATCH * SEQ) / 64), blk, 0, stream>>>(
      x, w_qkv, qkvb, BATCH * SEQ, QKV_N, HID);

  // bf16 MFMA flash attention -> att (f32)
  attn_mfma<<<dim3(BATCH * NH, SEQ / 64), blk, 0, stream>>>(qkvb, att);

  // out projection (fp32, known-good)
  gemm_nt<<<dim3(HID / 64, (BATCH * SEQ) / 64), blk, 0, stream>>>(
      att, w_out, b_out, out, BATCH * SEQ, HID, HID);
}

// Round 3
// 164.275 us; speedup vs baseline: 3.9052x; 2.1803x over previous
//
#include <hip/hip_runtime.h>
#include <hip/hip_bf16.h>
#include <cstdint>
#include <cstddef>

#define SEQ    2048
#define BATCH  2
#define HID    768
#define NH     12
#define HD     64
#define QKV_N  2304

typedef __attribute__((ext_vector_type(8))) short bf16x8;
typedef __attribute__((ext_vector_type(4))) float f32x4;

static __device__ __forceinline__ short f2bf(float x) {
  __hip_bfloat16 h = __float2bfloat16(x);  // RNE
  short s;
  __builtin_memcpy(&s, &h, 2);
  return s;
}

// ---------------------------------------------------------------------------
// Elementwise f32 -> bf16 (n must be a multiple of 8; all our sizes are).
// ---------------------------------------------------------------------------
__global__ __launch_bounds__(256)
void cvt_f32_bf16(const float* __restrict__ src, short* __restrict__ dst, int n) {
  const int i = (blockIdx.x * 256 + threadIdx.x) * 8;
  if (i >= n) return;
  const float4 a = *reinterpret_cast<const float4*>(src + i);
  const float4 b = *reinterpret_cast<const float4*>(src + i + 4);
  bf16x8 o;
  o[0] = f2bf(a.x); o[1] = f2bf(a.y); o[2] = f2bf(a.z); o[3] = f2bf(a.w);
  o[4] = f2bf(b.x); o[5] = f2bf(b.y); o[6] = f2bf(b.z); o[7] = f2bf(b.w);
  *reinterpret_cast<bf16x8*>(dst + i) = o;
}

// ---------------------------------------------------------------------------
// bf16 MFMA GEMM NT: C[M,N] = A[M,K] * B[N,K]^T (+ bias), fp32 accumulate.
// m97 structure: 128x128 tile, BK=64, 256 threads = 4 waves (2x2), each wave
// a 64x64 sub-tile (4x4 fragments of 16x16x32). Linear LDS + global_load_lds
// width 16 (dest = wave-uniform base + lane*16; source per-lane), 2-barrier
// loop (compiler drains vmcnt at the second barrier).
// Requires M%128==0, N%128==0, K%64==0.
// ---------------------------------------------------------------------------
template <bool BF16_OUT>
__global__ __launch_bounds__(256)
void gemm_nt_mfma(const short* __restrict__ A, const short* __restrict__ B,
                  const float* __restrict__ bias,
                  float* __restrict__ Cf, short* __restrict__ Cb,
                  int M, int N, int K) {
  __shared__ short As[128][64];   // 16 KB
  __shared__ short Bs[128][64];   // 16 KB

  const int t = threadIdx.x;
  const int w = t >> 6;        // wave 0..3
  const int l = t & 63;
  const int g = l >> 4;        // 0..3
  const int n = l & 15;

  const int m0 = blockIdx.y * 128;
  const int n0 = blockIdx.x * 128;
  const int wr = (w >> 1) * 64;   // wave row offset within tile
  const int wc = (w & 1) * 64;    // wave col offset within tile

  // Staging: wave w fills rows [w*32, w*32+32) of As and Bs, 4 chunks of
  // 8 rows (1 KB each). Lane l -> row += l>>3, elem col (l&7)*8.
  const int srow = w * 32 + (l >> 3);
  const int scol = (l & 7) * 8;
  const short* Ag = A + (size_t)(m0 + srow) * K + scol;
  const short* Bg = B + (size_t)(n0 + srow) * K + scol;

  f32x4 acc[4][4] = {};

  for (int k0 = 0; k0 < K; k0 += 64) {
    __syncthreads();   // prior iteration's LDS reads complete
#pragma unroll
    for (int it = 0; it < 4; ++it) {
      __builtin_amdgcn_global_load_lds(
          (const __attribute__((address_space(1))) void*)(Ag + (size_t)(it * 8) * K + k0),
          (__attribute__((address_space(3))) void*)(&As[w * 32 + it * 8][0]),
          16, 0, 0);
    }
#pragma unroll
    for (int it = 0; it < 4; ++it) {
      __builtin_amdgcn_global_load_lds(
          (const __attribute__((address_space(1))) void*)(Bg + (size_t)(it * 8) * K + k0),
          (__attribute__((address_space(3))) void*)(&Bs[w * 32 + it * 8][0]),
          16, 0, 0);
    }
    __syncthreads();   // vmcnt(0) drained here by compiler

#pragma unroll
    for (int kk = 0; kk < 2; ++kk) {
      bf16x8 af[4], bfr[4];
#pragma unroll
      for (int m = 0; m < 4; ++m)
        af[m] = *reinterpret_cast<const bf16x8*>(&As[wr + m * 16 + n][kk * 32 + g * 8]);
#pragma unroll
      for (int j = 0; j < 4; ++j)
        bfr[j] = *reinterpret_cast<const bf16x8*>(&Bs[wc + j * 16 + n][kk * 32 + g * 8]);
#pragma unroll
      for (int m = 0; m < 4; ++m)
#pragma unroll
        for (int j = 0; j < 4; ++j)
          acc[m][j] = __builtin_amdgcn_mfma_f32_16x16x32_bf16(af[m], bfr[j], acc[m][j], 0, 0, 0);
    }
  }

  // Epilogue. D layout: row = g*4 + r, col = n (per 16x16 fragment).
#pragma unroll
  for (int m = 0; m < 4; ++m) {
#pragma unroll
    for (int r = 0; r < 4; ++r) {
      const size_t row = m0 + wr + m * 16 + g * 4 + r;
#pragma unroll
      for (int j = 0; j < 4; ++j) {
        const int col = n0 + wc + j * 16 + n;
        float v = acc[m][j][r];
        if (bias) v += bias[col];
        if (BF16_OUT) Cb[row * N + col] = f2bf(v);
        else          Cf[row * N + col] = v;
      }
    }
  }
}

// ---------------------------------------------------------------------------
// Flash attention, bf16 MFMA (known-good from round 2; epilogue now bf16).
// Grid (BATCH*NH, SEQ/64), block 256 (4 waves). Wave w owns q-rows
// [q0+16w, q0+16w+16). qkv is bf16 [B*SEQ][2304], col = qkv*768 + h*64 + d.
// ---------------------------------------------------------------------------
__global__ __launch_bounds__(256)
void attn_mfma(const short* __restrict__ qkv, short* __restrict__ att) {
  const int bh = blockIdx.x;           // 0..23
  const int qt = blockIdx.y;           // 0..31
  const int b  = bh / NH;
  const int h  = bh % NH;
  const int q0 = qt * 64;

  const int t = threadIdx.x;
  const int w = t >> 6;                // wave 0..3
  const int l = t & 63;
  const int g = l >> 4;                // k-group 0..3
  const int n = l & 15;                // frag row/col index

  __shared__ short Kx[64][72];
  __shared__ short Vt[64][72];
  __shared__ short Ps[4][16][72];

  const short* baseq = qkv + (size_t)b * SEQ * QKV_N + h * HD;
  const short* Kg    = baseq + HID;
  const short* Vg    = baseq + 2 * HID;

  // ---- Q A-fragments: loaded once, kept in registers ----
  bf16x8 qf[2];
  {
    const short* qrow = baseq + (size_t)(q0 + w * 16 + n) * QKV_N;
#pragma unroll
    for (int c = 0; c < 2; ++c)
      qf[c] = *reinterpret_cast<const bf16x8*>(qrow + c * 32 + g * 8);
  }

  f32x4 o[4] = {{0.f,0.f,0.f,0.f},{0.f,0.f,0.f,0.f},
                {0.f,0.f,0.f,0.f},{0.f,0.f,0.f,0.f}};
  float mrow[4] = {-3e38f, -3e38f, -3e38f, -3e38f};
  float lrow[4] = {0.f, 0.f, 0.f, 0.f};

  const int sr  = t >> 2;              // staging row 0..63
  const int sdb = t & 3;               // staging 16-wide d block
  const int vys = sr ^ (sdb << 4);     // swizzled y for Vt writes

  for (int y0 = 0; y0 < SEQ; y0 += 64) {
    __syncthreads();

    // ---- stage K (row-major) ----
    {
      const short* kr = Kg + (size_t)(y0 + sr) * QKV_N + sdb * 16;
      bf16x8 k0 = *reinterpret_cast<const bf16x8*>(kr);
      bf16x8 k1 = *reinterpret_cast<const bf16x8*>(kr + 8);
      *reinterpret_cast<bf16x8*>(&Kx[sr][sdb * 16])     = k0;
      *reinterpret_cast<bf16x8*>(&Kx[sr][sdb * 16 + 8]) = k1;

      // ---- stage V (transposed, swizzled) ----
      const short* vr = Vg + (size_t)(y0 + sr) * QKV_N + sdb * 16;
      bf16x8 v0 = *reinterpret_cast<const bf16x8*>(vr);
      bf16x8 v1 = *reinterpret_cast<const bf16x8*>(vr + 8);
#pragma unroll
      for (int j = 0; j < 8; ++j) Vt[sdb * 16 + j][vys] = v0[j];
#pragma unroll
      for (int j = 0; j < 8; ++j) Vt[sdb * 16 + 8 + j][vys] = v1[j];
    }
    __syncthreads();

    // ---- QK^T ----
    f32x4 sc[4] = {{0.f,0.f,0.f,0.f},{0.f,0.f,0.f,0.f},
                   {0.f,0.f,0.f,0.f},{0.f,0.f,0.f,0.f}};
#pragma unroll
    for (int c = 0; c < 2; ++c) {
#pragma unroll
      for (int kt = 0; kt < 4; ++kt) {
        bf16x8 kb = *reinterpret_cast<const bf16x8*>(&Kx[kt * 16 + n][c * 32 + g * 8]);
        sc[kt] = __builtin_amdgcn_mfma_f32_16x16x32_bf16(qf[c], kb, sc[kt], 0, 0, 0);
      }
    }
#pragma unroll
    for (int kt = 0; kt < 4; ++kt)
#pragma unroll
      for (int r = 0; r < 4; ++r)
        sc[kt][r] *= 0.125f;

    // ---- online softmax ----
#pragma unroll
    for (int r = 0; r < 4; ++r) {
      float pm = fmaxf(fmaxf(sc[0][r], sc[1][r]), fmaxf(sc[2][r], sc[3][r]));
      pm = fmaxf(pm, __shfl_xor(pm, 1, 16));
      pm = fmaxf(pm, __shfl_xor(pm, 2, 16));
      pm = fmaxf(pm, __shfl_xor(pm, 4, 16));
      pm = fmaxf(pm, __shfl_xor(pm, 8, 16));
      const float mnew = fmaxf(mrow[r], pm);
      const float corr = __expf(mrow[r] - mnew);
      mrow[r] = mnew;
      float psum = 0.f;
#pragma unroll
      for (int kt = 0; kt < 4; ++kt) {
        const float p = __expf(sc[kt][r] - mnew);
        psum += p;
        Ps[w][g * 4 + r][kt * 16 + n] = f2bf(p);
      }
      lrow[r] = lrow[r] * corr + psum;
      o[0][r] *= corr; o[1][r] *= corr; o[2][r] *= corr; o[3][r] *= corr;
    }

    // ---- PV ----
#pragma unroll
    for (int c = 0; c < 2; ++c) {
      bf16x8 pa = *reinterpret_cast<const bf16x8*>(&Ps[w][n][c * 32 + g * 8]);
#pragma unroll
      for (int dt = 0; dt < 4; ++dt) {
        bf16x8 vb = *reinterpret_cast<const bf16x8*>(
            &Vt[dt * 16 + n][(c * 32 + g * 8) ^ (dt << 4)]);
        o[dt] = __builtin_amdgcn_mfma_f32_16x16x32_bf16(pa, vb, o[dt], 0, 0, 0);
      }
    }
  }

  // ---- epilogue: normalize, write bf16 ----
#pragma unroll
  for (int r = 0; r < 4; ++r) {
    float lt = lrow[r];
    lt += __shfl_xor(lt, 1, 16);
    lt += __shfl_xor(lt, 2, 16);
    lt += __shfl_xor(lt, 4, 16);
    lt += __shfl_xor(lt, 8, 16);
    const float linv = 1.f / lt;
    short* orow = att + (size_t)(b * SEQ + q0 + w * 16 + g * 4 + r) * HID
                      + h * HD + n;
    orow[0]  = f2bf(o[0][r] * linv);
    orow[16] = f2bf(o[1][r] * linv);
    orow[32] = f2bf(o[2][r] * linv);
    orow[48] = f2bf(o[3][r] * linv);
  }
}

// ---------------------------------------------------------------------------
extern "C" void kernel_launch(void* const* d_in, const int* in_sizes, int n_in,
                              void* d_out, int out_size, void* d_ws, size_t ws_size,
                              hipStream_t stream) {
  const float* x     = (const float*)d_in[0];  // [2,2048,768]
  const float* w_qkv = (const float*)d_in[1];  // [2304,768]
  const float* w_out = (const float*)d_in[2];  // [768,768]
  const float* b_out = (const float*)d_in[3];  // [768]
  float* out = (float*)d_out;                  // [2,2048,768]

  const int NX = BATCH * SEQ * HID;   // 3,145,728
  const int NWQ = QKV_N * HID;        // 1,769,472
  const int NWO = HID * HID;          //   589,824

  char* ws = (char*)d_ws;
  short* xb   = (short*)ws;                         ws += (size_t)NX  * 2;
  short* wqb  = (short*)ws;                         ws += (size_t)NWQ * 2;
  short* wob  = (short*)ws;                         ws += (size_t)NWO * 2;
  short* qkvb = (short*)ws;                         ws += (size_t)BATCH * SEQ * QKV_N * 2;
  short* attb = (short*)ws;                         // [4096,768] bf16
  // total ~36.2 MB of workspace

  const dim3 blk(256);

  cvt_f32_bf16<<<dim3(NX  / (256 * 8)), blk, 0, stream>>>(x,     xb,  NX);
  cvt_f32_bf16<<<dim3(NWQ / (256 * 8)), blk, 0, stream>>>(w_qkv, wqb, NWQ);
  cvt_f32_bf16<<<dim3(NWO / (256 * 8)), blk, 0, stream>>>(w_out, wob, NWO);

  // QKV projection: [4096,2304] = xb @ wqb^T  (bf16 out)
  gemm_nt_mfma<true><<<dim3(QKV_N / 128, (BATCH * SEQ) / 128), blk, 0, stream>>>(
      xb, wqb, nullptr, nullptr, qkvb, BATCH * SEQ, QKV_N, HID);

  // bf16 MFMA flash attention -> attb (bf16)
  attn_mfma<<<dim3(BATCH * NH, SEQ / 64), blk, 0, stream>>>(qkvb, attb);

  // out projection: out = attb @ wob^T + b_out  (f32 out)
  gemm_nt_mfma<false><<<dim3(HID / 128, (BATCH * SEQ) / 128), blk, 0, stream>>>(
      attb, wob, b_out, out, nullptr, BATCH * SEQ, HID, HID);
}

// Round 4
// 145.473 us; speedup vs baseline: 4.4100x; 1.1292x over previous
//
#include <hip/hip_runtime.h>
#include <hip/hip_bf16.h>
#include <cstdint>
#include <cstddef>

#define SEQ    2048
#define BATCH  2
#define HID    768
#define NH     12
#define HD     64
#define QKV_N  2304

typedef __attribute__((ext_vector_type(8))) short bf16x8;
typedef __attribute__((ext_vector_type(4))) float f32x4;

static __device__ __forceinline__ short f2bf(float x) {
  __hip_bfloat16 h = __float2bfloat16(x);  // RNE
  short s;
  __builtin_memcpy(&s, &h, 2);
  return s;
}
static __device__ __forceinline__ float bf2f(short s) {
  __hip_bfloat16 h;
  __builtin_memcpy(&h, &s, 2);
  return __bfloat162float(h);
}

// ---------------------------------------------------------------------------
// Elementwise f32 -> bf16 (n must be a multiple of 8; all our sizes are).
// ---------------------------------------------------------------------------
__global__ __launch_bounds__(256)
void cvt_f32_bf16(const float* __restrict__ src, short* __restrict__ dst, int n) {
  const int i = (blockIdx.x * 256 + threadIdx.x) * 8;
  if (i >= n) return;
  const float4 a = *reinterpret_cast<const float4*>(src + i);
  const float4 b = *reinterpret_cast<const float4*>(src + i + 4);
  bf16x8 o;
  o[0] = f2bf(a.x); o[1] = f2bf(a.y); o[2] = f2bf(a.z); o[3] = f2bf(a.w);
  o[4] = f2bf(b.x); o[5] = f2bf(b.y); o[6] = f2bf(b.z); o[7] = f2bf(b.w);
  *reinterpret_cast<bf16x8*>(dst + i) = o;
}

// ---------------------------------------------------------------------------
// bf16 MFMA GEMM NT (m97 structure, known-good from round 3).
// ---------------------------------------------------------------------------
template <bool BF16_OUT>
__global__ __launch_bounds__(256)
void gemm_nt_mfma(const short* __restrict__ A, const short* __restrict__ B,
                  const float* __restrict__ bias,
                  float* __restrict__ Cf, short* __restrict__ Cb,
                  int M, int N, int K) {
  __shared__ short As[128][64];   // 16 KB
  __shared__ short Bs[128][64];   // 16 KB

  const int t = threadIdx.x;
  const int w = t >> 6;
  const int l = t & 63;
  const int g = l >> 4;
  const int n = l & 15;

  const int m0 = blockIdx.y * 128;
  const int n0 = blockIdx.x * 128;
  const int wr = (w >> 1) * 64;
  const int wc = (w & 1) * 64;

  const int srow = w * 32 + (l >> 3);
  const int scol = (l & 7) * 8;
  const short* Ag = A + (size_t)(m0 + srow) * K + scol;
  const short* Bg = B + (size_t)(n0 + srow) * K + scol;

  f32x4 acc[4][4] = {};

  for (int k0 = 0; k0 < K; k0 += 64) {
    __syncthreads();
#pragma unroll
    for (int it = 0; it < 4; ++it) {
      __builtin_amdgcn_global_load_lds(
          (const __attribute__((address_space(1))) void*)(Ag + (size_t)(it * 8) * K + k0),
          (__attribute__((address_space(3))) void*)(&As[w * 32 + it * 8][0]),
          16, 0, 0);
    }
#pragma unroll
    for (int it = 0; it < 4; ++it) {
      __builtin_amdgcn_global_load_lds(
          (const __attribute__((address_space(1))) void*)(Bg + (size_t)(it * 8) * K + k0),
          (__attribute__((address_space(3))) void*)(&Bs[w * 32 + it * 8][0]),
          16, 0, 0);
    }
    __syncthreads();

#pragma unroll
    for (int kk = 0; kk < 2; ++kk) {
      bf16x8 af[4], bfr[4];
#pragma unroll
      for (int m = 0; m < 4; ++m)
        af[m] = *reinterpret_cast<const bf16x8*>(&As[wr + m * 16 + n][kk * 32 + g * 8]);
#pragma unroll
      for (int j = 0; j < 4; ++j)
        bfr[j] = *reinterpret_cast<const bf16x8*>(&Bs[wc + j * 16 + n][kk * 32 + g * 8]);
#pragma unroll
      for (int m = 0; m < 4; ++m)
#pragma unroll
        for (int j = 0; j < 4; ++j)
          acc[m][j] = __builtin_amdgcn_mfma_f32_16x16x32_bf16(af[m], bfr[j], acc[m][j], 0, 0, 0);
    }
  }

#pragma unroll
  for (int m = 0; m < 4; ++m) {
#pragma unroll
    for (int r = 0; r < 4; ++r) {
      const size_t row = m0 + wr + m * 16 + g * 4 + r;
#pragma unroll
      for (int j = 0; j < 4; ++j) {
        const int col = n0 + wc + j * 16 + n;
        float v = acc[m][j][r];
        if (bias) v += bias[col];
        if (BF16_OUT) Cb[row * N + col] = f2bf(v);
        else          Cf[row * N + col] = v;
      }
    }
  }
}

// ---------------------------------------------------------------------------
// Flash attention, bf16 MFMA, SWAPPED operand structure.
//   S^T = mfma(A=K, B=Q)  -> lane owns q = l&15, 16 S values (kv-axis local)
//   softmax: 15 local fmax + 2 shfl (xor16/xor32); m,l,corr lane-scalars
//   P written to plain Ps[q][y] as 4x ds_write_b64 (contiguous r-runs)
//   O^T = mfma(A=V^T, B=P^T): V^T frag = same b128 Vt read as before,
//   P^T frag = linear b128 read; epilogue 4x short4 global stores.
// Q pre-scaled by 0.125 (exact in bf16) at load.
// ---------------------------------------------------------------------------
__global__ __launch_bounds__(256)
void attn_mfma(const short* __restrict__ qkv, short* __restrict__ att) {
  const int bh = blockIdx.x;           // 0..23
  const int qt = blockIdx.y;           // 0..31
  const int b  = bh / NH;
  const int h  = bh % NH;
  const int q0 = qt * 64;

  const int t = threadIdx.x;
  const int w = t >> 6;                // wave 0..3
  const int l = t & 63;
  const int g = l >> 4;                // k-slot group 0..3
  const int n = l & 15;                // q column owned by this lane

  __shared__ short Kx[64][72];
  __shared__ short Vt[64][72];
  __shared__ short Ps[4][16][72];      // per-wave P[q][y], linear y

  const short* baseq = qkv + (size_t)b * SEQ * QKV_N + h * HD;
  const short* Kg    = baseq + HID;
  const short* Vg    = baseq + 2 * HID;

  // ---- Q B-fragments (col = q = n), pre-scaled by 0.125 (exact) ----
  bf16x8 qf[2];
  {
    const short* qrow = baseq + (size_t)(q0 + w * 16 + n) * QKV_N;
#pragma unroll
    for (int c = 0; c < 2; ++c) {
      bf16x8 raw = *reinterpret_cast<const bf16x8*>(qrow + c * 32 + g * 8);
#pragma unroll
      for (int j = 0; j < 8; ++j) qf[c][j] = f2bf(bf2f(raw[j]) * 0.125f);
    }
  }

  f32x4 o[4] = {{0.f,0.f,0.f,0.f},{0.f,0.f,0.f,0.f},
                {0.f,0.f,0.f,0.f},{0.f,0.f,0.f,0.f}};
  float mrow = -3e38f;
  float lrow = 0.f;

  const int sr  = t >> 2;              // staging row 0..63
  const int sdb = t & 3;               // staging 16-wide d block
  const int vys = sr ^ (sdb << 4);     // swizzled y for Vt writes

  for (int y0 = 0; y0 < SEQ; y0 += 64) {
    __syncthreads();

    // ---- stage K (row-major) ----
    {
      const short* kr = Kg + (size_t)(y0 + sr) * QKV_N + sdb * 16;
      bf16x8 k0 = *reinterpret_cast<const bf16x8*>(kr);
      bf16x8 k1 = *reinterpret_cast<const bf16x8*>(kr + 8);
      *reinterpret_cast<bf16x8*>(&Kx[sr][sdb * 16])     = k0;
      *reinterpret_cast<bf16x8*>(&Kx[sr][sdb * 16 + 8]) = k1;

      // ---- stage V (transposed, swizzled) ----
      const short* vr = Vg + (size_t)(y0 + sr) * QKV_N + sdb * 16;
      bf16x8 v0 = *reinterpret_cast<const bf16x8*>(vr);
      bf16x8 v1 = *reinterpret_cast<const bf16x8*>(vr + 8);
#pragma unroll
      for (int j = 0; j < 8; ++j) Vt[sdb * 16 + j][vys] = v0[j];
#pragma unroll
      for (int j = 0; j < 8; ++j) Vt[sdb * 16 + 8 + j][vys] = v1[j];
    }
    __syncthreads();

    // ---- QK^T swapped: sc[kt] = S^T tile, lane holds
    //      S[kv = kt*16 + g*4 + r][q = n] in sc[kt][r] ----
    f32x4 sc[4] = {{0.f,0.f,0.f,0.f},{0.f,0.f,0.f,0.f},
                   {0.f,0.f,0.f,0.f},{0.f,0.f,0.f,0.f}};
#pragma unroll
    for (int c = 0; c < 2; ++c) {
#pragma unroll
      for (int kt = 0; kt < 4; ++kt) {
        bf16x8 kb = *reinterpret_cast<const bf16x8*>(&Kx[kt * 16 + n][c * 32 + g * 8]);
        sc[kt] = __builtin_amdgcn_mfma_f32_16x16x32_bf16(kb, qf[c], sc[kt], 0, 0, 0);
      }
    }

    // ---- online softmax: all state per-lane (q = n) ----
    {
      float pm = fmaxf(fmaxf(sc[0][0], sc[0][1]), fmaxf(sc[0][2], sc[0][3]));
#pragma unroll
      for (int kt = 1; kt < 4; ++kt) {
        pm = fmaxf(pm, fmaxf(fmaxf(sc[kt][0], sc[kt][1]),
                             fmaxf(sc[kt][2], sc[kt][3])));
      }
      pm = fmaxf(pm, __shfl_xor(pm, 16));
      pm = fmaxf(pm, __shfl_xor(pm, 32));
      const float mnew = fmaxf(mrow, pm);
      const float corr = __expf(mrow - mnew);
      mrow = mnew;
      float psum = 0.f;
#pragma unroll
      for (int kt = 0; kt < 4; ++kt) {
        short4 pk;
        float p0 = __expf(sc[kt][0] - mnew);
        float p1 = __expf(sc[kt][1] - mnew);
        float p2 = __expf(sc[kt][2] - mnew);
        float p3 = __expf(sc[kt][3] - mnew);
        psum += (p0 + p1) + (p2 + p3);
        pk.x = f2bf(p0); pk.y = f2bf(p1); pk.z = f2bf(p2); pk.w = f2bf(p3);
        // P[q=n][y = kt*16 + g*4 + (0..3)] — contiguous b64 write
        *reinterpret_cast<short4*>(&Ps[w][n][kt * 16 + g * 4]) = pk;
      }
      lrow = lrow * corr + psum;
#pragma unroll
      for (int dt = 0; dt < 4; ++dt)
#pragma unroll
        for (int r = 0; r < 4; ++r) o[dt][r] *= corr;
    }
    // Ps is wave-local: ds_write -> ds_read ordering handled by lgkmcnt.

    // ---- PV swapped: o[dt] = O^T tile, lane holds
    //      O[q = n][d = dt*16 + g*4 + r] in o[dt][r] ----
#pragma unroll
    for (int c = 0; c < 2; ++c) {
      bf16x8 pb = *reinterpret_cast<const bf16x8*>(&Ps[w][n][c * 32 + g * 8]);
#pragma unroll
      for (int dt = 0; dt < 4; ++dt) {
        bf16x8 va = *reinterpret_cast<const bf16x8*>(
            &Vt[dt * 16 + n][(c * 32 + g * 8) ^ (dt << 4)]);
        o[dt] = __builtin_amdgcn_mfma_f32_16x16x32_bf16(va, pb, o[dt], 0, 0, 0);
      }
    }
  }

  // ---- epilogue: reduce l across g-lanes, normalize, 4x short4 store ----
  {
    float lt = lrow;
    lt += __shfl_xor(lt, 16);
    lt += __shfl_xor(lt, 32);
    const float linv = 1.f / lt;
    short* orow = att + (size_t)(b * SEQ + q0 + w * 16 + n) * HID + h * HD;
#pragma unroll
    for (int dt = 0; dt < 4; ++dt) {
      short4 ov;
      ov.x = f2bf(o[dt][0] * linv);
      ov.y = f2bf(o[dt][1] * linv);
      ov.z = f2bf(o[dt][2] * linv);
      ov.w = f2bf(o[dt][3] * linv);
      *reinterpret_cast<short4*>(&orow[dt * 16 + g * 4]) = ov;
    }
  }
}

// ---------------------------------------------------------------------------
extern "C" void kernel_launch(void* const* d_in, const int* in_sizes, int n_in,
                              void* d_out, int out_size, void* d_ws, size_t ws_size,
                              hipStream_t stream) {
  const float* x     = (const float*)d_in[0];  // [2,2048,768]
  const float* w_qkv = (const float*)d_in[1];  // [2304,768]
  const float* w_out = (const float*)d_in[2];  // [768,768]
  const float* b_out = (const float*)d_in[3];  // [768]
  float* out = (float*)d_out;                  // [2,2048,768]

  const int NX  = BATCH * SEQ * HID;   // 3,145,728
  const int NWQ = QKV_N * HID;         // 1,769,472
  const int NWO = HID * HID;           //   589,824

  char* ws = (char*)d_ws;
  short* xb   = (short*)ws;  ws += (size_t)NX  * 2;
  short* wqb  = (short*)ws;  ws += (size_t)NWQ * 2;
  short* wob  = (short*)ws;  ws += (size_t)NWO * 2;
  short* qkvb = (short*)ws;  ws += (size_t)BATCH * SEQ * QKV_N * 2;
  short* attb = (short*)ws;  // [4096,768] bf16

  const dim3 blk(256);

  cvt_f32_bf16<<<dim3(NX  / (256 * 8)), blk, 0, stream>>>(x,     xb,  NX);
  cvt_f32_bf16<<<dim3(NWQ / (256 * 8)), blk, 0, stream>>>(w_qkv, wqb, NWQ);
  cvt_f32_bf16<<<dim3(NWO / (256 * 8)), blk, 0, stream>>>(w_out, wob, NWO);

  // QKV projection: [4096,2304] = xb @ wqb^T  (bf16 out)
  gemm_nt_mfma<true><<<dim3(QKV_N / 128, (BATCH * SEQ) / 128), blk, 0, stream>>>(
      xb, wqb, nullptr, nullptr, qkvb, BATCH * SEQ, QKV_N, HID);

  // bf16 MFMA flash attention (swapped structure) -> attb (bf16)
  attn_mfma<<<dim3(BATCH * NH, SEQ / 64), blk, 0, stream>>>(qkvb, attb);

  // out projection: out = attb @ wob^T + b_out  (f32 out)
  gemm_nt_mfma<false><<<dim3(HID / 128, (BATCH * SEQ) / 128), blk, 0, stream>>>(
      attb, wob, b_out, out, nullptr, BATCH * SEQ, HID, HID);
}